// Round 5
// baseline (540.503 us; speedup 1.0000x reference)
//
#include <hip/hip_runtime.h>
#include <cstdint>
#include <cstddef>

// Problem constants (B=2, S=2048 -> T=4096 tokens)
#define TT 4096
#define DD 1024
#define MM 2048
#define EE 8
#define NPAIR 8192   // TT * top_k(2)

typedef unsigned short u16;
typedef __bf16 bf16x8 __attribute__((ext_vector_type(8)));
typedef float f32x4 __attribute__((ext_vector_type(4)));
typedef u16 u16x8 __attribute__((ext_vector_type(8)));
typedef __attribute__((address_space(3))) void* lds_vp;
typedef __attribute__((address_space(1))) const void* gbl_cvp;

__device__ __forceinline__ void async16(u16* l, const u16* g) {
  __builtin_amdgcn_global_load_lds((gbl_cvp)(const void*)g, (lds_vp)(void*)l, 16, 0, 0);
}

__device__ __forceinline__ u16 f2bf(float f) {
  uint32_t u = __builtin_bit_cast(uint32_t, f);
  u += 0x7fffu + ((u >> 16) & 1u);   // RNE
  return (u16)(u >> 16);
}
__device__ __forceinline__ float bf2f(u16 h) {
  uint32_t u = ((uint32_t)h) << 16;
  return __builtin_bit_cast(float, u);
}

// ---------------- router + X->bf16 convert fused ----------------
__global__ void router_kernel(const float* __restrict__ X, const float* __restrict__ Wr,
                              int* __restrict__ tok_idx, float* __restrict__ wpair,
                              u16* __restrict__ Xbf) {
  int wave = threadIdx.x >> 6;
  int lane = threadIdx.x & 63;
  int t = blockIdx.x * 4 + wave;
  const float4* x4 = (const float4*)(X + (size_t)t * DD);
  float acc[EE];
#pragma unroll
  for (int e = 0; e < EE; e++) acc[e] = 0.f;
#pragma unroll
  for (int i = 0; i < 4; i++) {
    float4 xv = x4[i * 64 + lane];
    ushort4 o;
    o.x = f2bf(xv.x); o.y = f2bf(xv.y); o.z = f2bf(xv.z); o.w = f2bf(xv.w);
    *(ushort4*)&Xbf[(size_t)t * DD + (size_t)(i * 64 + lane) * 4] = o;
    const float4* wr4 = (const float4*)(Wr + (size_t)(i * 256 + lane * 4) * EE);
    float xs[4] = {xv.x, xv.y, xv.z, xv.w};
#pragma unroll
    for (int c = 0; c < 4; c++) {
      float4 wa = wr4[c * 2 + 0];
      float4 wb = wr4[c * 2 + 1];
      acc[0] += xs[c] * wa.x; acc[1] += xs[c] * wa.y;
      acc[2] += xs[c] * wa.z; acc[3] += xs[c] * wa.w;
      acc[4] += xs[c] * wb.x; acc[5] += xs[c] * wb.y;
      acc[6] += xs[c] * wb.z; acc[7] += xs[c] * wb.w;
    }
  }
#pragma unroll
  for (int off = 32; off > 0; off >>= 1)
#pragma unroll
    for (int e = 0; e < EE; e++) acc[e] += __shfl_xor(acc[e], off);
  if (lane == 0) {
    float mx = acc[0];
#pragma unroll
    for (int e = 1; e < EE; e++) mx = fmaxf(mx, acc[e]);
    float p[EE], s = 0.f;
#pragma unroll
    for (int e = 0; e < EE; e++) { p[e] = __expf(acc[e] - mx); s += p[e]; }
    float inv = 1.f / s;
#pragma unroll
    for (int e = 0; e < EE; e++) p[e] *= inv;
    int i0 = 0;
#pragma unroll
    for (int e = 1; e < EE; e++) if (p[e] > p[i0]) i0 = e;
    int i1 = (i0 == 0) ? 1 : 0;
#pragma unroll
    for (int e = 0; e < EE; e++) if (e != i0 && p[e] > p[i1]) i1 = e;
    float denom = p[i0] + p[i1] + 1e-8f;
    tok_idx[t * 2 + 0] = i0;
    tok_idx[t * 2 + 1] = i1;
    wpair[t * 2 + 0] = p[i0] / denom;
    wpair[t * 2 + 1] = p[i1] / denom;
  }
}

// ---------------- single-block bucketing via LDS atomics ----------------
__global__ void bucket_kernel(const int* __restrict__ tok_idx, int* __restrict__ offsets,
                              int* __restrict__ bucket) {
  __shared__ int lcnt[EE];
  __shared__ int lcur[EE];
  int tid = threadIdx.x;   // 1024 threads
  if (tid < EE) lcnt[tid] = 0;
  __syncthreads();
  for (int i = tid; i < NPAIR; i += 1024) atomicAdd(&lcnt[tok_idx[i]], 1);
  __syncthreads();
  if (tid == 0) {
    int s = 0;
    for (int e = 0; e < EE; e++) {
      offsets[e] = s;
      lcur[e] = s;
      s += lcnt[e];
    }
    offsets[EE] = s;
  }
  __syncthreads();
  for (int i = tid; i < NPAIR; i += 1024) {
    int e = tok_idx[i];
    int pos = atomicAdd(&lcur[e], 1);
    bucket[pos] = i;
  }
}

// ---------------- fused transpose+convert for all 3 weight tensors ----------------
// [E][R][C] f32 -> [E][C][R] bf16, 64x64 tiles. bid encodes {matrix, tile}.
__global__ __launch_bounds__(256)
void transpose_all(const float* __restrict__ Wg, const float* __restrict__ Wu,
                   const float* __restrict__ Wo, u16* __restrict__ WtG,
                   u16* __restrict__ WtU, u16* __restrict__ WtO) {
  __shared__ float tile[64][65];   // [c][r], +1 pad
  int bid = blockIdx.x;
  int mid = bid >> 9;              // 512 tiles per matrix
  int tix = bid & 511;
  const float* in; u16* out; int R, C, cx, ry, e;
  if (mid < 2) {
    in = (mid == 0) ? Wg : Wu;  out = (mid == 0) ? WtG : WtU;
    R = DD; C = MM;
    e = tix >> 6;                  // 64 tiles per expert (32 c x 2... no: 32x16/8)
    int t = tix & 63;              // (C/64)*(R/64)/8 = 32*16/8 = 64
    cx = t & 31; ry = t >> 5;      // ry in 0..1 ... wait need 16 -> use full decode below
    // full decode: tiles per expert = (C/64)*(R/64) = 32*16 = 512/8 = 64
    ry = (t >> 5) + ((tix & 63) >> 5) * 0;  // placeholder (recomputed below)
    // recompute cleanly:
    e = tix / 512; // always 0 here; use uniform decode instead:
    int tt = tix;  // 0..511 over e*64... decode: e = tt>>6, local = tt&63, cx = local&31, ry = local>>5 gives ry 0..1 only (WRONG for 16 rows)
    // Correct: tiles per expert = 32 (cx) * 16 (ry) = 512 -> but we have 512 total for 8 experts.
    // So: 512 total tiles = 8 e * 64 tiles, 64 = 32 cx * 2?? No: per-expert tile count = (2048/64)*(1024/64)=32*16=512.
    // => 512 tiles can't cover 8 experts. Use 4096 tiles per G/U matrix instead (handled by grid sizing).
    e = 0; (void)e;
    cx = 0; ry = 0;
  }
  // --- The above decode is replaced by uniform math (kept simple & correct): ---
  // total tiles: G:4096, U:4096, O:4096 (each matrix: 8 experts x 512 tiles)
  {
    int m, t;
    if (bid < 4096)       { m = 0; t = bid; }
    else if (bid < 8192)  { m = 1; t = bid - 4096; }
    else                  { m = 2; t = bid - 8192; }
    if (m == 0) { in = Wg; out = WtG; R = DD; C = MM; }
    else if (m == 1) { in = Wu; out = WtU; R = DD; C = MM; }
    else { in = Wo; out = WtO; R = MM; C = DD; }
    int tpe = (R >> 6) * (C >> 6);   // 512
    e = t / tpe; t -= e * tpe;
    int ctiles = C >> 6;
    ry = t / ctiles; cx = t - ry * ctiles;
  }
  const float* I = in + (size_t)e * R * C;
  u16* O = out + (size_t)e * R * C;
  int c0 = cx * 64, r0 = ry * 64;
  int th = threadIdx.x;
  {
    int cq = th & 15;
    int rb = th >> 4;
#pragma unroll
    for (int i = 0; i < 4; i++) {
      int r = rb + i * 16;
      float4 v = *(const float4*)&I[(size_t)(r0 + r) * C + c0 + cq * 4];
      tile[cq * 4 + 0][r] = v.x;
      tile[cq * 4 + 1][r] = v.y;
      tile[cq * 4 + 2][r] = v.z;
      tile[cq * 4 + 3][r] = v.w;
    }
  }
  __syncthreads();
  {
    int rseg = (th & 7) * 8;
    int cc = th >> 3;
#pragma unroll
    for (int i = 0; i < 2; i++) {
      int c = cc + i * 32;
      u16x8 o;
#pragma unroll
      for (int k = 0; k < 8; k++) o[k] = f2bf(tile[c][rseg + k]);
      *(u16x8*)&O[(size_t)(c0 + c) * R + r0 + rseg] = o;
    }
  }
}

// Map row-tile index rt -> (expert, row0, rows). Tiles never cross expert boundaries.
__device__ __forceinline__ bool tile_map(const int* __restrict__ offsets, int x,
                                         int& expert, int& row0, int& rows) {
  expert = -1;
#pragma unroll 1
  for (int e = 0; e < EE; e++) {
    int o0 = offsets[e], o1 = offsets[e + 1];
    int nt = (o1 - o0 + 127) >> 7;
    if (x < nt) { expert = e; row0 = o0 + (x << 7); rows = min(128, o1 - row0); return true; }
    x -= nt;
  }
  return false;
}

// ---------------- grouped MFMA GEMM, BK=64, rt-innermost grid ----------------
// Grid decode: xcd = bid&7 owns rt in [xcd*9, xcd*9+9); slot = bid>>3;
// rt_local = slot%9 (FASTEST -> 9 co-resident blocks share one B tile),
// n0 = (slot/9)*128.
// LDS swizzle (BK=64, 8 chunks of 16B/row): chunk c of row r at position c^(r&7).
// MODE 0: U = X*Wu + b_up            -> Hws (bf16)
// MODE 1: H = silu(X*Wg + b_gate)*U  -> Hws (bf16, in place over U)
// MODE 2: Ypart[pair] = w*(H*Wo + b_out)  (f32)
template <int MODE>
__global__ __launch_bounds__(256)
void moe_gemm(const u16* __restrict__ Aglob, const u16* __restrict__ Wt,
              const float* __restrict__ bias, u16* __restrict__ Hws,
              float* __restrict__ Ypart, const int* __restrict__ offsets,
              const int* __restrict__ bucket, const float* __restrict__ wpair) {
  constexpr int K = (MODE == 2) ? MM : DD;
  constexpr int N = (MODE == 2) ? DD : MM;

  int bid = blockIdx.x;
  int xcd = bid & 7, slot = bid >> 3;
  int n0i = slot / 9;
  int rloc = slot - n0i * 9;
  int rt = xcd * 9 + rloc;
  int n0 = n0i * 128;

  int expert, row0, rows;
  if (!tile_map(offsets, rt, expert, row0, rows)) return;

  __shared__ u16 Alds[128 * 64];
  __shared__ u16 Blds[128 * 64];

  int tid = threadIdx.x;
  int wave = tid >> 6, lane = tid & 63;
  int wm = wave >> 1, wn = wave & 1;
  int quad = lane >> 4, l15 = lane & 15;
  int rl8 = lane >> 3;                          // row-within-8 for staging
  int src_c = ((lane & 7) ^ rl8) * 8;           // source chunk elem offset (swizzle)

  // staging pointers: 4 rows per lane per matrix (rows wave*32 + 8j + rl8)
  const u16* Aptr[4];
  const u16* Bptr[4];
  u16* sA[4];
  u16* sB[4];
  const u16* Wbase = Wt + (size_t)expert * N * K + (size_t)n0 * K;
#pragma unroll
  for (int j = 0; j < 4; j++) {
    int r = wave * 32 + j * 8 + rl8;
    int rr = min(r, rows - 1);
    long arow;
    if (MODE == 2) arow = (long)(row0 + rr) * K;
    else           arow = (long)(bucket[row0 + rr] >> 1) * K;
    Aptr[j] = Aglob + arow + src_c;
    Bptr[j] = Wbase + (long)r * K + src_c;
    sA[j] = &Alds[(wave * 32 + j * 8) * 64];
    sB[j] = &Blds[(wave * 32 + j * 8) * 64];
  }

  // fragment read bases: row = {wm|wn}*64 + i*16 + l15, chunk c = s*4+quad at
  // position c ^ (l15&7); byte addr = row*128 + pos*16
  int pbase = (quad ^ (l15 & 7)) * 8;           // elems; s=1 adds XOR 4*8
  int arow_f = wm * 64 + l15;
  int brow_f = wn * 64 + l15;

  f32x4 acc[4][4];
#pragma unroll
  for (int i = 0; i < 4; i++)
#pragma unroll
    for (int j = 0; j < 4; j++) acc[i][j] = (f32x4){0, 0, 0, 0};

  for (int k0 = 0; k0 < K; k0 += 64) {
#pragma unroll
    for (int j = 0; j < 4; j++) {
      async16(sA[j], Aptr[j]);
      async16(sB[j], Bptr[j]);
      Aptr[j] += 64; Bptr[j] += 64;
    }
    __syncthreads();
#pragma unroll
    for (int s = 0; s < 2; s++) {
      int poff = pbase ^ (s * 32);              // elems: (c^..)*8, s flips bit2 of chunk -> +-32 elems
      bf16x8 af[4], bf[4];
#pragma unroll
      for (int i = 0; i < 4; i++) {
        af[i] = *(const bf16x8*)&Alds[(arow_f + i * 16) * 64 + poff];
        bf[i] = *(const bf16x8*)&Blds[(brow_f + i * 16) * 64 + poff];
      }
#pragma unroll
      for (int i = 0; i < 4; i++)
#pragma unroll
        for (int j = 0; j < 4; j++)
          acc[i][j] = __builtin_amdgcn_mfma_f32_16x16x32_bf16(af[i], bf[j], acc[i][j], 0, 0, 0);
    }
    __syncthreads();
  }

  // epilogue: C/D layout col = lane&15, row = quad*4 + r
#pragma unroll
  for (int i = 0; i < 4; i++) {
    int lrb = wm * 64 + i * 16 + quad * 4;
#pragma unroll
    for (int j = 0; j < 4; j++) {
      int gc = n0 + wn * 64 + j * 16 + l15;
      float bv = bias[expert * N + gc];
#pragma unroll
      for (int r = 0; r < 4; r++) {
        int lr = lrb + r;
        if (lr < rows) {
          int grow = row0 + lr;
          float v = acc[i][j][r] + bv;
          if (MODE == 0) {
            Hws[(size_t)grow * MM + gc] = f2bf(v);
          } else if (MODE == 1) {
            float u = bf2f(Hws[(size_t)grow * MM + gc]);
            float sg = v / (1.f + __expf(-v));
            Hws[(size_t)grow * MM + gc] = f2bf(sg * u);
          } else {
            int p = bucket[grow];
            float w = wpair[p];
            Ypart[(size_t)p * DD + gc] = w * v;
          }
        }
      }
    }
  }
}

// ---------------- combine the two expert contributions per token ----------------
__global__ void combine_kernel(const float* __restrict__ Ypart, float* __restrict__ out) {
  int i = blockIdx.x * 256 + threadIdx.x;   // over TT*DD/4
  int t = i >> 8;
  int c4 = i & 255;
  const float4* y0 = (const float4*)(Ypart + (size_t)(2 * t) * DD) + c4;
  const float4* y1 = (const float4*)(Ypart + (size_t)(2 * t + 1) * DD) + c4;
  float4 a = *y0, b = *y1;
  float4 o;
  o.x = a.x + b.x; o.y = a.y + b.y; o.z = a.z + b.z; o.w = a.w + b.w;
  ((float4*)out)[i] = o;
}

extern "C" void kernel_launch(void* const* d_in, const int* in_sizes, int n_in,
                              void* d_out, int out_size, void* d_ws, size_t ws_size,
                              hipStream_t stream) {
  const float* residual = (const float*)d_in[0];
  const float* W_router = (const float*)d_in[1];
  const float* W_gate   = (const float*)d_in[2];
  const float* b_gate   = (const float*)d_in[3];
  const float* W_up     = (const float*)d_in[4];
  const float* b_up     = (const float*)d_in[5];
  const float* W_out    = (const float*)d_in[6];
  const float* b_out    = (const float*)d_in[7];
  float* out = (float*)d_out;

  char* ws = (char*)d_ws;
  int*   tok_idx = (int*)(ws + 0);                       // 8192 ints
  float* wpair   = (float*)(ws + 32768);                 // 8192 floats
  int*   offsets = (int*)(ws + 65536);                   // 9 ints
  int*   bucket  = (int*)(ws + 65536 + 512);             // 8192 ints
  u16*   Xbf  = (u16*)(ws + 131072);                                     // 8 MB
  u16*   WtG  = Xbf + (size_t)TT * DD;                                   // 32 MB  [E][M][D]
  u16*   WtU  = WtG + (size_t)EE * MM * DD;                              // 32 MB  [E][M][D]
  u16*   WtO  = WtU + (size_t)EE * MM * DD;                              // 32 MB  [E][D][M]
  u16*   Hws  = WtO + (size_t)EE * DD * MM;                              // 32 MB  [8192][M]
  float* Ypart = (float*)(Hws + (size_t)NPAIR * MM);                     // 32 MB  [8192][D]

  router_kernel<<<dim3(TT / 4), dim3(256), 0, stream>>>(residual, W_router, tok_idx, wpair, Xbf);
  bucket_kernel<<<dim3(1), dim3(1024), 0, stream>>>(tok_idx, offsets, bucket);
  transpose_all<<<dim3(3 * 4096), dim3(256), 0, stream>>>(W_gate, W_up, W_out, WtG, WtU, WtO);
  // grouped GEMMs: 8 XCDs x (16|8 n-tiles x 9 row tiles), rt innermost
  moe_gemm<0><<<dim3(8 * 16 * 9), dim3(256), 0, stream>>>(Xbf, WtU, b_up,   Hws, Ypart, offsets, bucket, wpair);
  moe_gemm<1><<<dim3(8 * 16 * 9), dim3(256), 0, stream>>>(Xbf, WtG, b_gate, Hws, Ypart, offsets, bucket, wpair);
  moe_gemm<2><<<dim3(8 * 8 * 9),  dim3(256), 0, stream>>>(Hws, WtO, b_out,  Hws, Ypart, offsets, bucket, wpair);
  combine_kernel<<<dim3(TT * DD / 4 / 256), dim3(256), 0, stream>>>(Ypart, out);
}